// Round 9
// baseline (208.703 us; speedup 1.0000x reference)
//
#include <hip/hip_runtime.h>

typedef unsigned short ushort_t;
typedef unsigned char uchar_t;
typedef __attribute__((ext_vector_type(8))) short bf16x8;
typedef __attribute__((ext_vector_type(4))) float f32x4;
typedef __attribute__((ext_vector_type(16))) float f32x16;
typedef __attribute__((ext_vector_type(8))) int v8i;

__device__ __forceinline__ unsigned short f2bf(float f) {
  union { float f; unsigned int u; } v; v.f = f;
  unsigned int r = v.u + 0x7FFFu + ((v.u >> 16) & 1u);
  return (unsigned short)(r >> 16);
}

__device__ __forceinline__ float bf2f(unsigned short u) {
  union { unsigned int i; float f; } v; v.i = ((unsigned int)u) << 16;
  return v.f;
}

__device__ __forceinline__ void gl_lds16(const void* gsrc, void* ldst) {
  __builtin_amdgcn_global_load_lds(
      (const __attribute__((address_space(1))) void*)gsrc,
      (__attribute__((address_space(3))) void*)ldst, 16, 0, 0);
}

__device__ __forceinline__ int frag_idx(int oc, int ci) {
  return (((oc>>4)*8 + (ci>>5))<<9) + ((((ci>>3)&3)*16 + (oc&15))<<3) + (ci&7);
}

// ---------------------------------------------------------------------------
// K1: fragment-major bf16 weight bank Wf[640][256] (Q=wq, K=wk, V=w128@wv)
//     + bias_all[640].  Blocks 0..511: copy/cast QK.  512..639: V-fold, 1 oc
//     per block (128-way parallel; wv rows L2-shared across blocks).
// ---------------------------------------------------------------------------
__global__ __launch_bounds__(256) void k1_weights(
    const float* __restrict__ wq, const float* __restrict__ bq,
    const float* __restrict__ wk, const float* __restrict__ bk,
    const float* __restrict__ wv, const float* __restrict__ bv,
    const float* __restrict__ w128,
    ushort_t* __restrict__ Wf, float* __restrict__ bias_all)
{
  const int ci = threadIdx.x;
  const int oc = blockIdx.x;
  if (oc < 512) {
    const float v = (oc < 256) ? wq[oc*256 + ci] : wk[(oc-256)*256 + ci];
    Wf[frag_idx(oc, ci)] = f2bf(v);
    if (ci == 0) bias_all[oc] = (oc < 256) ? bq[oc] : bk[oc-256];
  } else {
    const int o = oc - 512;
    const float* wr = w128 + (size_t)o*256;
    float a = 0.f;
    for (int co = 0; co < 256; co++) a += wr[co] * wv[co*256 + ci];
    Wf[frag_idx(oc, ci)] = f2bf(a);
    if (ci == 0) {
      float s = 0.f;
      for (int co = 0; co < 256; co++) s += wr[co] * bv[co];
      bias_all[oc] = s;
    }
  }
}

// ---------------------------------------------------------------------------
// K2: MFMA feature GEMM (bf16 16x16x32 internally). Grid (256, 2):
//   x = 64-px tile, y splits the output dim: y=0 -> ot 0..4, y=1 -> ot 5..9.
//   ot 0..3 -> Qf8, 4..7 -> Kf8 (fp8 e4m3 chunks, 1 KB each, 16B/lane),
//   ot 8..9 -> V fp32 [src*8+b][oc][hw]
// ---------------------------------------------------------------------------
__global__ __launch_bounds__(256) void k2_features(
    const float* __restrict__ x4, const float* __restrict__ x3,
    const ushort_t* __restrict__ Wf, const float* __restrict__ bias_all,
    uchar_t* __restrict__ Qf8, uchar_t* __restrict__ Kf8, float* __restrict__ V)
{
  __shared__ ushort_t Af[32*512];      // 32 KB
  __shared__ ushort_t Wl[2][32*512];   // 2 x 32 KB
  __shared__ ushort_t Lt[64*72];       // repack buffer (bf16)

  const int tid = threadIdx.x;
  const int w = tid >> 6, lane = tid & 63;
  const int mrow = lane & 15, quad = lane >> 4;
  const int ln31 = lane & 31, half = lane >> 5;

  const int px0 = blockIdx.x * 64;
  const int src = px0 >> 13, b = (px0 >> 10) & 7, hw0 = px0 & 1023;
  const float* xp = (src ? x3 : x4) + (size_t)b*262144;

  const int ot0 = blockIdx.y * 5;      // y=0: ot 0..4, y=1: ot 5..9

  for (int kb = 0; kb < 8; kb++)
    gl_lds16(Wf + ((size_t)((ot0*4 + w)*8 + kb)<<9) + lane*8,
             &Wl[ot0&1][(w*8+kb)*512]);

  {
    const int hw = hw0 + w*16 + mrow;
    for (int kb = 0; kb < 8; kb++) {
      const int ch0 = kb*32 + quad*8;
      bf16x8 pk;
      #pragma unroll
      for (int j = 0; j < 8; j++)
        ((ushort_t*)&pk)[j] = f2bf(xp[(size_t)(ch0 + j)*1024 + hw]);
      *(bf16x8*)&Af[(w*8 + kb)*512 + lane*8] = pk;
    }
  }
  __syncthreads();

  for (int ot = ot0; ot < ot0 + 5; ot++) {
    const int nbuf = (ot+1) & 1, cbuf = ot & 1;
    if (ot + 1 < ot0 + 5) {
      for (int kb = 0; kb < 8; kb++)
        gl_lds16(Wf + ((size_t)(((ot+1)*4 + w)*8 + kb)<<9) + lane*8,
                 &Wl[nbuf][(w*8+kb)*512]);
      asm volatile("s_waitcnt vmcnt(8)" ::: "memory");
    } else {
      asm volatile("s_waitcnt vmcnt(0)" ::: "memory");
    }

    f32x4 acc[4];
    #pragma unroll
    for (int lg = 0; lg < 4; lg++) acc[lg] = (f32x4){0.f,0.f,0.f,0.f};
    #pragma unroll
    for (int kb = 0; kb < 8; kb++) {
      const bf16x8 a = *(const bf16x8*)&Wl[cbuf][(w*8 + kb)*512 + lane*8];
      #pragma unroll
      for (int lg = 0; lg < 4; lg++) {
        const bf16x8 bx = *(const bf16x8*)&Af[(lg*8 + kb)*512 + lane*8];
        acc[lg] = __builtin_amdgcn_mfma_f32_16x16x32_bf16(a, bx, acc[lg], 0, 0, 0);
      }
    }
    const int ocl = w*16 + quad*4;
    const float4 bias4 = *(const float4*)&bias_all[ot*64 + ocl];

    if (ot < 8) {
      __syncthreads();
      #pragma unroll
      for (int lg = 0; lg < 4; lg++) {
        const int px = lg*16 + mrow;
        ushort4 pk;
        pk.x = f2bf(acc[lg][0] + bias4.x);
        pk.y = f2bf(acc[lg][1] + bias4.y);
        pk.z = f2bf(acc[lg][2] + bias4.z);
        pk.w = f2bf(acc[lg][3] + bias4.w);
        *(ushort4*)&Lt[px*72 + ocl] = pk;
      }
      __syncthreads();
      // emit one fp8 chunk per wave: wave w -> g = w>>1, e = w&1
      const int g = w >> 1, e = w & 1;
      const int row = g*32 + ln31;
      const ushort_t* lp = &Lt[row*72 + e*32 + half*8];
      float fl[8], fh[8];
      #pragma unroll
      for (int j = 0; j < 8; j++) { fl[j] = bf2f(lp[j]); fh[j] = bf2f(lp[16+j]); }
      int w0 = __builtin_amdgcn_cvt_pk_fp8_f32(fl[0], fl[1], 0, 0);
      w0     = __builtin_amdgcn_cvt_pk_fp8_f32(fl[2], fl[3], w0, 1);
      int w1 = __builtin_amdgcn_cvt_pk_fp8_f32(fl[4], fl[5], 0, 0);
      w1     = __builtin_amdgcn_cvt_pk_fp8_f32(fl[6], fl[7], w1, 1);
      int w2 = __builtin_amdgcn_cvt_pk_fp8_f32(fh[0], fh[1], 0, 0);
      w2     = __builtin_amdgcn_cvt_pk_fp8_f32(fh[2], fh[3], w2, 1);
      int w3 = __builtin_amdgcn_cvt_pk_fp8_f32(fh[4], fh[5], 0, 0);
      w3     = __builtin_amdgcn_cvt_pk_fp8_f32(fh[6], fh[7], w3, 1);
      uchar_t* dst = (ot < 4) ? Qf8 : Kf8;
      const size_t chunk = (size_t)((px0>>5) + g)*8 + (ot&3)*2 + e;
      int4 pk4; pk4.x = w0; pk4.y = w1; pk4.z = w2; pk4.w = w3;
      *(int4*)(dst + (chunk<<10) + lane*16) = pk4;
    } else {
      const int ocv0 = (ot-8)*64 + ocl;
      float* vb = V + (((size_t)(src*8 + b)*128) << 10) + hw0;
      #pragma unroll
      for (int lg = 0; lg < 4; lg++) {
        vb[(size_t)(ocv0+0)*1024 + lg*16 + mrow] = acc[lg][0] + bias4.x;
        vb[(size_t)(ocv0+1)*1024 + lg*16 + mrow] = acc[lg][1] + bias4.y;
        vb[(size_t)(ocv0+2)*1024 + lg*16 + mrow] = acc[lg][2] + bias4.z;
        vb[(size_t)(ocv0+3)*1024 + lg*16 + mrow] = acc[lg][3] + bias4.w;
      }
    }
  }
}

// ---------------------------------------------------------------------------
// K3: MX-scaled fp8 MFMA 32x32x64 (unit scales = plain fp8 at 2x rate).
//   Block = 256 rows x one key-batch (1024 cols), 4 waves x 64 rows.
//   __launch_bounds__(256, 1): per-wave reg budget 512 -> no spill; achieved
//   occupancy still 2 blocks/CU (LDS 64 KB is the binding cap).
//   K staged via gl_lds in 32 KB double-buffered stages, 8 barriers/block.
//   Pm layout: [batch(16)][row(16384)]
// ---------------------------------------------------------------------------
__global__ __launch_bounds__(256, 1) void k3_smax(
    const uchar_t* __restrict__ Qf8, const uchar_t* __restrict__ Kf8,
    float* __restrict__ Pm)
{
  __shared__ __align__(16) uchar_t Kl[2][32768];   // 2 x 32 KB

  const int tid = threadIdx.x;
  const int bt = blockIdx.x >> 6;      // key-batch 0..15
  const int rt = blockIdx.x & 63;      // row-tile (256 rows)
  const int w = tid >> 6, lane = tid & 63;
  const int ln31 = lane & 31, half = lane >> 5;

  const int rgb = rt*8 + w*2;          // wave's first row-grp32
  const int ph = (blockIdx.x & 1)*4;   // stage-phase rotation (8 stages)

  // prologue: stage s=0: 32 chunks (4 cgl x 8 kp); wave w -> c = w*8..w*8+7
  #pragma unroll
  for (int q = 0; q < 8; q++) {
    const int c = w*8 + q;             // cgl = c>>3, kp = c&7
    const int cg = bt*32 + ph*4 + (c>>3);
    gl_lds16(Kf8 + (((size_t)cg*8 + (c&7))<<10) + lane*16, &Kl[0][c*1024]);
  }

  // Q fragments: 2 rg x 4 u-windows, v8i each (64 VGPR), resident whole kernel
  v8i qa[2][4];
  #pragma unroll
  for (int rg = 0; rg < 2; rg++)
    #pragma unroll
    for (int u = 0; u < 4; u++) {
      const int4 p0 = *(const int4*)(Qf8 + (((size_t)(rgb + rg)*8 + 2*u+0)<<10) + lane*16);
      const int4 p1 = *(const int4*)(Qf8 + (((size_t)(rgb + rg)*8 + 2*u+1)<<10) + lane*16);
      qa[rg][u] = (v8i){p0.x, p0.y, p0.z, p0.w, p1.x, p1.y, p1.z, p1.w};
    }

  f32x16 zv;
  #pragma unroll
  for (int i = 0; i < 16; i++) zv[i] = 0.f;
  f32x16 rmax0, rmax1;
  #pragma unroll
  for (int i = 0; i < 16; i++) { rmax0[i] = -3.4e38f; rmax1[i] = -3.4e38f; }

  for (int s = 0; s < 8; s++) {
    __syncthreads();                   // drains prefetch for stage s
    if (s < 7) {
      const int sn = (s + 1 + ph) & 7;
      #pragma unroll
      for (int q = 0; q < 8; q++) {
        const int c = w*8 + q;
        const int cg = bt*32 + sn*4 + (c>>3);
        gl_lds16(Kf8 + (((size_t)cg*8 + (c&7))<<10) + lane*16,
                 &Kl[(s+1)&1][c*1024]);
      }
    }
    const uchar_t* kl = Kl[s & 1];
    #pragma unroll
    for (int cgl = 0; cgl < 4; cgl++) {
      f32x16 a0 = zv, a1 = zv;
      #pragma unroll
      for (int u = 0; u < 4; u++) {
        const int4 b0 = *(const int4*)&kl[(cgl*8 + 2*u+0)*1024 + lane*16];
        const int4 b1 = *(const int4*)&kl[(cgl*8 + 2*u+1)*1024 + lane*16];
        const v8i bu = (v8i){b0.x, b0.y, b0.z, b0.w, b1.x, b1.y, b1.z, b1.w};
        a0 = __builtin_amdgcn_mfma_scale_f32_32x32x64_f8f6f4(
            qa[0][u], bu, a0, 0, 0, 0, 0x7F7F7F7F, 0, 0x7F7F7F7F);
        a1 = __builtin_amdgcn_mfma_scale_f32_32x32x64_f8f6f4(
            qa[1][u], bu, a1, 0, 0, 0, 0x7F7F7F7F, 0, 0x7F7F7F7F);
      }
      #pragma unroll
      for (int i = 0; i < 16; i++) {
        rmax0[i] = fmaxf(rmax0[i], a0[i]);
        rmax1[i] = fmaxf(rmax1[i], a1[i]);
      }
    }
  }

  // epilogue: per-row max over 32 cols (5 xor-shuffles in each 32-lane half)
  // C/D: col = lane&31, row = (reg&3) + 8*(reg>>2) + 4*half (shape-determined)
  #pragma unroll
  for (int rg = 0; rg < 2; rg++) {
    #pragma unroll
    for (int e = 0; e < 16; e++) {
      float v = (rg == 0) ? rmax0[e] : rmax1[e];
      v = fmaxf(v, __shfl_xor(v, 1));
      v = fmaxf(v, __shfl_xor(v, 2));
      v = fmaxf(v, __shfl_xor(v, 4));
      v = fmaxf(v, __shfl_xor(v, 8));
      v = fmaxf(v, __shfl_xor(v, 16));
      if (ln31 == 0) {
        const int row = rt*256 + w*64 + rg*32 + (e&3) + 8*(e>>2) + 4*half;
        Pm[(size_t)bt*16384 + row] = v;
      }
    }
  }
}

// ---------------------------------------------------------------------------
// K5: fused gates + output.  Block = one (b, ch) pair, 256 threads x 4 hw.
//   Recomputes its gate row's softmax from Pm (deterministic, identical across
//   blocks sharing the row): logits = mean over 8 batch-maxes * scale.
//   out[b][ch][hw] = softmax_hw(logit) * V + b128.  ch: [x34|a_x4|x43|b_x3]
// ---------------------------------------------------------------------------
__global__ __launch_bounds__(256) void k5_out(
    const float* __restrict__ V, const float* __restrict__ Pm,
    const float* __restrict__ b128, float* __restrict__ out)
{
  __shared__ float xw[2][4];
  const int tid = threadIdx.x;
  const int ch = blockIdx.x & 511, b = blockIdx.x >> 9;
  const int blk = ch >> 7, o = ch & 127;
  const int gidx = (blk == 0) ? 2 : (blk == 1) ? 0 : (blk == 2) ? 1 : 3;
  const int src = (blk >= 2) ? 1 : 0;
  const int qset = gidx >> 1, side = gidx & 1;

  // logits for hw = tid*4 .. tid*4+3 (coalesced float4 per batch)
  const float4* Pm4 = (const float4*)(Pm + (size_t)side*8*16384 + qset*8192 + b*1024);
  float4 l = {0.f, 0.f, 0.f, 0.f};
  #pragma unroll
  for (int t = 0; t < 8; t++) {
    const float4 p = Pm4[t*4096 + tid];
    l.x += p.x; l.y += p.y; l.z += p.z; l.w += p.w;
  }
  const float sc = 0.125f * 0.0625f;   // mean over 8 batches * 1/sqrt(256)
  l.x *= sc; l.y *= sc; l.z *= sc; l.w *= sc;

  const int w = tid >> 6, lane = tid & 63;
  float m = fmaxf(fmaxf(l.x, l.y), fmaxf(l.z, l.w));
  #pragma unroll
  for (int d = 1; d < 64; d <<= 1) m = fmaxf(m, __shfl_xor(m, d));
  if (lane == 0) xw[0][w] = m;
  __syncthreads();
  m = fmaxf(fmaxf(xw[0][0], xw[0][1]), fmaxf(xw[0][2], xw[0][3]));

  float4 e;
  e.x = expf(l.x - m); e.y = expf(l.y - m);
  e.z = expf(l.z - m); e.w = expf(l.w - m);
  float s = e.x + e.y + e.z + e.w;
  #pragma unroll
  for (int d = 1; d < 64; d <<= 1) s += __shfl_xor(s, d);
  if (lane == 0) xw[1][w] = s;
  __syncthreads();
  s = xw[1][0] + xw[1][1] + xw[1][2] + xw[1][3];
  const float inv = 1.f / s;

  const int hw0 = tid << 2;
  const float4 v = *(const float4*)&V[((size_t)((src*8 + b)*128 + o) << 10) + hw0];
  const float bias = b128[o];
  float4 r;
  r.x = e.x*inv*v.x + bias; r.y = e.y*inv*v.y + bias;
  r.z = e.z*inv*v.z + bias; r.w = e.w*inv*v.w + bias;
  *(float4*)&out[((size_t)(b*512 + ch) << 10) + hw0] = r;
}

// ---------------------------------------------------------------------------
extern "C" void kernel_launch(void* const* d_in, const int* in_sizes, int n_in,
                              void* d_out, int out_size, void* d_ws, size_t ws_size,
                              hipStream_t stream)
{
  const float* x4   = (const float*)d_in[0];
  const float* x3   = (const float*)d_in[1];
  const float* wq   = (const float*)d_in[2];
  const float* bq   = (const float*)d_in[3];
  const float* wk   = (const float*)d_in[4];
  const float* bk   = (const float*)d_in[5];
  const float* wv   = (const float*)d_in[6];
  const float* bv   = (const float*)d_in[7];
  const float* w128 = (const float*)d_in[8];
  const float* b128 = (const float*)d_in[9];
  float* out = (float*)d_out;

  char* ws = (char*)d_ws;
  uchar_t*  Qf8 = (uchar_t*)ws;  ws += (size_t)512*8*1024;      // 4 MB
  uchar_t*  Kf8 = (uchar_t*)ws;  ws += (size_t)512*8*1024;      // 4 MB
  float*    V   = (float*)ws;    ws += (size_t)2*8*128*1024*4;  // 8 MB
  float*    Pm  = (float*)ws;    ws += (size_t)16*16384*4;      // 1 MB
  ushort_t* Wf  = (ushort_t*)ws; ws += (size_t)640*256*2;       // 320 KB
  float* bias_all = (float*)ws;                                 // 2.5 KB

  k1_weights <<<640,          256, 0, stream>>>(wq, bq, wk, bk, wv, bv, w128, Wf, bias_all);
  k2_features<<<dim3(256, 2), 256, 0, stream>>>(x4, x3, Wf, bias_all, Qf8, Kf8, V);
  k3_smax    <<<1024,         256, 0, stream>>>(Qf8, Kf8, Pm);
  k5_out     <<<4096,         256, 0, stream>>>(V, Pm, b128, out);
}

// Round 10
// 200.929 us; speedup vs baseline: 1.0387x; 1.0387x over previous
//
#include <hip/hip_runtime.h>

typedef unsigned short ushort_t;
typedef unsigned char uchar_t;
typedef __attribute__((ext_vector_type(8))) short bf16x8;
typedef __attribute__((ext_vector_type(4))) float f32x4;
typedef __attribute__((ext_vector_type(16))) float f32x16;
typedef __attribute__((ext_vector_type(8))) int v8i;

__device__ __forceinline__ unsigned short f2bf(float f) {
  union { float f; unsigned int u; } v; v.f = f;
  unsigned int r = v.u + 0x7FFFu + ((v.u >> 16) & 1u);
  return (unsigned short)(r >> 16);
}

__device__ __forceinline__ float bf2f(unsigned short u) {
  union { unsigned int i; float f; } v; v.i = ((unsigned int)u) << 16;
  return v.f;
}

__device__ __forceinline__ void gl_lds16(const void* gsrc, void* ldst) {
  __builtin_amdgcn_global_load_lds(
      (const __attribute__((address_space(1))) void*)gsrc,
      (__attribute__((address_space(3))) void*)ldst, 16, 0, 0);
}

__device__ __forceinline__ int frag_idx(int oc, int ci) {
  return (((oc>>4)*8 + (ci>>5))<<9) + ((((ci>>3)&3)*16 + (oc&15))<<3) + (ci&7);
}

// ---------------------------------------------------------------------------
// K1: fragment-major bf16 weight bank Wf[640][256] (Q=wq, K=wk, V=w128@wv)
//     + bias_all[640].  Blocks 0..511: copy/cast QK.  512..639: V-fold, 1 oc
//     per block.
// ---------------------------------------------------------------------------
__global__ __launch_bounds__(256) void k1_weights(
    const float* __restrict__ wq, const float* __restrict__ bq,
    const float* __restrict__ wk, const float* __restrict__ bk,
    const float* __restrict__ wv, const float* __restrict__ bv,
    const float* __restrict__ w128,
    ushort_t* __restrict__ Wf, float* __restrict__ bias_all)
{
  const int ci = threadIdx.x;
  const int oc = blockIdx.x;
  if (oc < 512) {
    const float v = (oc < 256) ? wq[oc*256 + ci] : wk[(oc-256)*256 + ci];
    Wf[frag_idx(oc, ci)] = f2bf(v);
    if (ci == 0) bias_all[oc] = (oc < 256) ? bq[oc] : bk[oc-256];
  } else {
    const int o = oc - 512;
    const float* wr = w128 + (size_t)o*256;
    float a = 0.f;
    for (int co = 0; co < 256; co++) a += wr[co] * wv[co*256 + ci];
    Wf[frag_idx(oc, ci)] = f2bf(a);
    if (ci == 0) {
      float s = 0.f;
      for (int co = 0; co < 256; co++) s += wr[co] * bv[co];
      bias_all[oc] = s;
    }
  }
}

// ---------------------------------------------------------------------------
// K2: MFMA feature GEMM (bf16 16x16x32 internally). Grid (256, 2):
//   x = 64-px tile, y splits the output dim: y=0 -> ot 0..4, y=1 -> ot 5..9.
//   ot 0..3 -> Qf8, 4..7 -> Kf8 (fp8 e4m3 chunks, 1 KB each, 16B/lane),
//   ot 8..9 -> V fp32 [src*8+b][oc][hw]
// ---------------------------------------------------------------------------
__global__ __launch_bounds__(256) void k2_features(
    const float* __restrict__ x4, const float* __restrict__ x3,
    const ushort_t* __restrict__ Wf, const float* __restrict__ bias_all,
    uchar_t* __restrict__ Qf8, uchar_t* __restrict__ Kf8, float* __restrict__ V)
{
  __shared__ ushort_t Af[32*512];      // 32 KB
  __shared__ ushort_t Wl[2][32*512];   // 2 x 32 KB
  __shared__ ushort_t Lt[64*72];       // repack buffer (bf16)

  const int tid = threadIdx.x;
  const int w = tid >> 6, lane = tid & 63;
  const int mrow = lane & 15, quad = lane >> 4;
  const int ln31 = lane & 31, half = lane >> 5;

  const int px0 = blockIdx.x * 64;
  const int src = px0 >> 13, b = (px0 >> 10) & 7, hw0 = px0 & 1023;
  const float* xp = (src ? x3 : x4) + (size_t)b*262144;

  const int ot0 = blockIdx.y * 5;      // y=0: ot 0..4, y=1: ot 5..9

  for (int kb = 0; kb < 8; kb++)
    gl_lds16(Wf + ((size_t)((ot0*4 + w)*8 + kb)<<9) + lane*8,
             &Wl[ot0&1][(w*8+kb)*512]);

  {
    const int hw = hw0 + w*16 + mrow;
    for (int kb = 0; kb < 8; kb++) {
      const int ch0 = kb*32 + quad*8;
      bf16x8 pk;
      #pragma unroll
      for (int j = 0; j < 8; j++)
        ((ushort_t*)&pk)[j] = f2bf(xp[(size_t)(ch0 + j)*1024 + hw]);
      *(bf16x8*)&Af[(w*8 + kb)*512 + lane*8] = pk;
    }
  }
  __syncthreads();

  for (int ot = ot0; ot < ot0 + 5; ot++) {
    const int nbuf = (ot+1) & 1, cbuf = ot & 1;
    if (ot + 1 < ot0 + 5) {
      for (int kb = 0; kb < 8; kb++)
        gl_lds16(Wf + ((size_t)(((ot+1)*4 + w)*8 + kb)<<9) + lane*8,
                 &Wl[nbuf][(w*8+kb)*512]);
      asm volatile("s_waitcnt vmcnt(8)" ::: "memory");
    } else {
      asm volatile("s_waitcnt vmcnt(0)" ::: "memory");
    }

    f32x4 acc[4];
    #pragma unroll
    for (int lg = 0; lg < 4; lg++) acc[lg] = (f32x4){0.f,0.f,0.f,0.f};
    #pragma unroll
    for (int kb = 0; kb < 8; kb++) {
      const bf16x8 a = *(const bf16x8*)&Wl[cbuf][(w*8 + kb)*512 + lane*8];
      #pragma unroll
      for (int lg = 0; lg < 4; lg++) {
        const bf16x8 bx = *(const bf16x8*)&Af[(lg*8 + kb)*512 + lane*8];
        acc[lg] = __builtin_amdgcn_mfma_f32_16x16x32_bf16(a, bx, acc[lg], 0, 0, 0);
      }
    }
    const int ocl = w*16 + quad*4;
    const float4 bias4 = *(const float4*)&bias_all[ot*64 + ocl];

    if (ot < 8) {
      __syncthreads();
      #pragma unroll
      for (int lg = 0; lg < 4; lg++) {
        const int px = lg*16 + mrow;
        ushort4 pk;
        pk.x = f2bf(acc[lg][0] + bias4.x);
        pk.y = f2bf(acc[lg][1] + bias4.y);
        pk.z = f2bf(acc[lg][2] + bias4.z);
        pk.w = f2bf(acc[lg][3] + bias4.w);
        *(ushort4*)&Lt[px*72 + ocl] = pk;
      }
      __syncthreads();
      // emit one fp8 chunk per wave: wave w -> g = w>>1, e = w&1
      const int g = w >> 1, e = w & 1;
      const int row = g*32 + ln31;
      const ushort_t* lp = &Lt[row*72 + e*32 + half*8];
      float fl[8], fh[8];
      #pragma unroll
      for (int j = 0; j < 8; j++) { fl[j] = bf2f(lp[j]); fh[j] = bf2f(lp[16+j]); }
      int w0 = __builtin_amdgcn_cvt_pk_fp8_f32(fl[0], fl[1], 0, 0);
      w0     = __builtin_amdgcn_cvt_pk_fp8_f32(fl[2], fl[3], w0, 1);
      int w1 = __builtin_amdgcn_cvt_pk_fp8_f32(fl[4], fl[5], 0, 0);
      w1     = __builtin_amdgcn_cvt_pk_fp8_f32(fl[6], fl[7], w1, 1);
      int w2 = __builtin_amdgcn_cvt_pk_fp8_f32(fh[0], fh[1], 0, 0);
      w2     = __builtin_amdgcn_cvt_pk_fp8_f32(fh[2], fh[3], w2, 1);
      int w3 = __builtin_amdgcn_cvt_pk_fp8_f32(fh[4], fh[5], 0, 0);
      w3     = __builtin_amdgcn_cvt_pk_fp8_f32(fh[6], fh[7], w3, 1);
      uchar_t* dst = (ot < 4) ? Qf8 : Kf8;
      const size_t chunk = (size_t)((px0>>5) + g)*8 + (ot&3)*2 + e;
      int4 pk4; pk4.x = w0; pk4.y = w1; pk4.z = w2; pk4.w = w3;
      *(int4*)(dst + (chunk<<10) + lane*16) = pk4;
    } else {
      const int ocv0 = (ot-8)*64 + ocl;
      float* vb = V + (((size_t)(src*8 + b)*128) << 10) + hw0;
      #pragma unroll
      for (int lg = 0; lg < 4; lg++) {
        vb[(size_t)(ocv0+0)*1024 + lg*16 + mrow] = acc[lg][0] + bias4.x;
        vb[(size_t)(ocv0+1)*1024 + lg*16 + mrow] = acc[lg][1] + bias4.y;
        vb[(size_t)(ocv0+2)*1024 + lg*16 + mrow] = acc[lg][2] + bias4.z;
        vb[(size_t)(ocv0+3)*1024 + lg*16 + mrow] = acc[lg][3] + bias4.w;
      }
    }
  }
}

// ---------------------------------------------------------------------------
// K3: MX-scaled fp8 MFMA 32x32x64 (unit scales = plain fp8 at 2x rate).
//   Block = 512 rows x one key-batch (1024 cols), 4 waves x 128 rows (4 rg32).
//   B-reuse x4: each LDS B-fragment feeds 4 MFMAs -> LDS port ~42% (was 86%).
//   1 block/CU by design: (256,1) gives 512-reg/wave budget, no spill.
//   K staged via gl_lds in 32 KB double-buffered stages, 8 barriers/block.
//   Pm layout: [batch(16)][row(16384)].  Grid 512.
// ---------------------------------------------------------------------------
__global__ __launch_bounds__(256, 1) void k3_smax(
    const uchar_t* __restrict__ Qf8, const uchar_t* __restrict__ Kf8,
    float* __restrict__ Pm)
{
  __shared__ __align__(16) uchar_t Kl[2][32768];   // 2 x 32 KB

  const int tid = threadIdx.x;
  const int bt = blockIdx.x >> 5;      // key-batch 0..15
  const int rt = blockIdx.x & 31;      // row-tile (512 rows)
  const int w = tid >> 6, lane = tid & 63;
  const int ln31 = lane & 31, half = lane >> 5;

  const int rgb = rt*16 + w*4;         // wave's first row-grp32 (owns 4)
  const int ph = (blockIdx.x & 1)*4;   // stage-phase rotation (8 stages)

  // prologue: stage s=0: 32 chunks (4 cgl x 8 kp); wave w -> c = w*8..w*8+7
  #pragma unroll
  for (int q = 0; q < 8; q++) {
    const int c = w*8 + q;             // cgl = c>>3, kp = c&7
    const int cg = bt*32 + ph*4 + (c>>3);
    gl_lds16(Kf8 + (((size_t)cg*8 + (c&7))<<10) + lane*16, &Kl[0][c*1024]);
  }

  // Q fragments: 4 rg x 4 u-windows, v8i each (128 VGPR), resident whole kernel
  v8i qa[4][4];
  #pragma unroll
  for (int rg = 0; rg < 4; rg++)
    #pragma unroll
    for (int u = 0; u < 4; u++) {
      const int4 p0 = *(const int4*)(Qf8 + (((size_t)(rgb + rg)*8 + 2*u+0)<<10) + lane*16);
      const int4 p1 = *(const int4*)(Qf8 + (((size_t)(rgb + rg)*8 + 2*u+1)<<10) + lane*16);
      qa[rg][u] = (v8i){p0.x, p0.y, p0.z, p0.w, p1.x, p1.y, p1.z, p1.w};
    }

  f32x16 zv;
  #pragma unroll
  for (int i = 0; i < 16; i++) zv[i] = 0.f;
  f32x16 rmax[4];
  #pragma unroll
  for (int rg = 0; rg < 4; rg++)
    #pragma unroll
    for (int i = 0; i < 16; i++) rmax[rg][i] = -3.4e38f;

  for (int s = 0; s < 8; s++) {
    __syncthreads();                   // drains prefetch for stage s
    if (s < 7) {
      const int sn = (s + 1 + ph) & 7;
      #pragma unroll
      for (int q = 0; q < 8; q++) {
        const int c = w*8 + q;
        const int cg = bt*32 + sn*4 + (c>>3);
        gl_lds16(Kf8 + (((size_t)cg*8 + (c&7))<<10) + lane*16,
                 &Kl[(s+1)&1][c*1024]);
      }
    }
    const uchar_t* kl = Kl[s & 1];
    #pragma unroll
    for (int cgl = 0; cgl < 4; cgl++) {
      f32x16 a0 = zv, a1 = zv, a2 = zv, a3 = zv;
      #pragma unroll
      for (int u = 0; u < 4; u++) {
        const int4 b0 = *(const int4*)&kl[(cgl*8 + 2*u+0)*1024 + lane*16];
        const int4 b1 = *(const int4*)&kl[(cgl*8 + 2*u+1)*1024 + lane*16];
        const v8i bu = (v8i){b0.x, b0.y, b0.z, b0.w, b1.x, b1.y, b1.z, b1.w};
        a0 = __builtin_amdgcn_mfma_scale_f32_32x32x64_f8f6f4(
            qa[0][u], bu, a0, 0, 0, 0, 0x7F7F7F7F, 0, 0x7F7F7F7F);
        a1 = __builtin_amdgcn_mfma_scale_f32_32x32x64_f8f6f4(
            qa[1][u], bu, a1, 0, 0, 0, 0x7F7F7F7F, 0, 0x7F7F7F7F);
        a2 = __builtin_amdgcn_mfma_scale_f32_32x32x64_f8f6f4(
            qa[2][u], bu, a2, 0, 0, 0, 0x7F7F7F7F, 0, 0x7F7F7F7F);
        a3 = __builtin_amdgcn_mfma_scale_f32_32x32x64_f8f6f4(
            qa[3][u], bu, a3, 0, 0, 0, 0x7F7F7F7F, 0, 0x7F7F7F7F);
      }
      #pragma unroll
      for (int i = 0; i < 16; i++) {
        rmax[0][i] = fmaxf(rmax[0][i], a0[i]);
        rmax[1][i] = fmaxf(rmax[1][i], a1[i]);
        rmax[2][i] = fmaxf(rmax[2][i], a2[i]);
        rmax[3][i] = fmaxf(rmax[3][i], a3[i]);
      }
    }
  }

  // epilogue: per-row max over 32 cols (5 xor-shuffles in each 32-lane half)
  // C/D: col = lane&31, row = (reg&3) + 8*(reg>>2) + 4*half (shape-determined)
  #pragma unroll
  for (int rg = 0; rg < 4; rg++) {
    #pragma unroll
    for (int e = 0; e < 16; e++) {
      float v = rmax[rg][e];
      v = fmaxf(v, __shfl_xor(v, 1));
      v = fmaxf(v, __shfl_xor(v, 2));
      v = fmaxf(v, __shfl_xor(v, 4));
      v = fmaxf(v, __shfl_xor(v, 8));
      v = fmaxf(v, __shfl_xor(v, 16));
      if (ln31 == 0) {
        const int row = rt*512 + w*128 + rg*32 + (e&3) + 8*(e>>2) + 4*half;
        Pm[(size_t)bt*16384 + row] = v;
      }
    }
  }
}

// ---------------------------------------------------------------------------
// K5: fused gates + output.  Block = one (b, ch) pair, 256 threads x 4 hw.
//   Recomputes its gate row's softmax from Pm (deterministic, identical across
//   blocks sharing the row): logits = mean over 8 batch-maxes * scale.
//   out[b][ch][hw] = softmax_hw(logit) * V + b128.  ch: [x34|a_x4|x43|b_x3]
// ---------------------------------------------------------------------------
__global__ __launch_bounds__(256) void k5_out(
    const float* __restrict__ V, const float* __restrict__ Pm,
    const float* __restrict__ b128, float* __restrict__ out)
{
  __shared__ float xw[2][4];
  const int tid = threadIdx.x;
  const int ch = blockIdx.x & 511, b = blockIdx.x >> 9;
  const int blk = ch >> 7, o = ch & 127;
  const int gidx = (blk == 0) ? 2 : (blk == 1) ? 0 : (blk == 2) ? 1 : 3;
  const int src = (blk >= 2) ? 1 : 0;
  const int qset = gidx >> 1, side = gidx & 1;

  // logits for hw = tid*4 .. tid*4+3 (coalesced float4 per batch)
  const float4* Pm4 = (const float4*)(Pm + (size_t)side*8*16384 + qset*8192 + b*1024);
  float4 l = {0.f, 0.f, 0.f, 0.f};
  #pragma unroll
  for (int t = 0; t < 8; t++) {
    const float4 p = Pm4[t*4096 + tid];
    l.x += p.x; l.y += p.y; l.z += p.z; l.w += p.w;
  }
  const float sc = 0.125f * 0.0625f;   // mean over 8 batches * 1/sqrt(256)
  l.x *= sc; l.y *= sc; l.z *= sc; l.w *= sc;

  const int w = tid >> 6, lane = tid & 63;
  float m = fmaxf(fmaxf(l.x, l.y), fmaxf(l.z, l.w));
  #pragma unroll
  for (int d = 1; d < 64; d <<= 1) m = fmaxf(m, __shfl_xor(m, d));
  if (lane == 0) xw[0][w] = m;
  __syncthreads();
  m = fmaxf(fmaxf(xw[0][0], xw[0][1]), fmaxf(xw[0][2], xw[0][3]));

  float4 e;
  e.x = expf(l.x - m); e.y = expf(l.y - m);
  e.z = expf(l.z - m); e.w = expf(l.w - m);
  float s = e.x + e.y + e.z + e.w;
  #pragma unroll
  for (int d = 1; d < 64; d <<= 1) s += __shfl_xor(s, d);
  if (lane == 0) xw[1][w] = s;
  __syncthreads();
  s = xw[1][0] + xw[1][1] + xw[1][2] + xw[1][3];
  const float inv = 1.f / s;

  const int hw0 = tid << 2;
  const float4 v = *(const float4*)&V[((size_t)((src*8 + b)*128 + o) << 10) + hw0];
  const float bias = b128[o];
  float4 r;
  r.x = e.x*inv*v.x + bias; r.y = e.y*inv*v.y + bias;
  r.z = e.z*inv*v.z + bias; r.w = e.w*inv*v.w + bias;
  *(float4*)&out[((size_t)(b*512 + ch) << 10) + hw0] = r;
}

// ---------------------------------------------------------------------------
extern "C" void kernel_launch(void* const* d_in, const int* in_sizes, int n_in,
                              void* d_out, int out_size, void* d_ws, size_t ws_size,
                              hipStream_t stream)
{
  const float* x4   = (const float*)d_in[0];
  const float* x3   = (const float*)d_in[1];
  const float* wq   = (const float*)d_in[2];
  const float* bq   = (const float*)d_in[3];
  const float* wk   = (const float*)d_in[4];
  const float* bk   = (const float*)d_in[5];
  const float* wv   = (const float*)d_in[6];
  const float* bv   = (const float*)d_in[7];
  const float* w128 = (const float*)d_in[8];
  const float* b128 = (const float*)d_in[9];
  float* out = (float*)d_out;

  char* ws = (char*)d_ws;
  uchar_t*  Qf8 = (uchar_t*)ws;  ws += (size_t)512*8*1024;      // 4 MB
  uchar_t*  Kf8 = (uchar_t*)ws;  ws += (size_t)512*8*1024;      // 4 MB
  float*    V   = (float*)ws;    ws += (size_t)2*8*128*1024*4;  // 8 MB
  float*    Pm  = (float*)ws;    ws += (size_t)16*16384*4;      // 1 MB
  ushort_t* Wf  = (ushort_t*)ws; ws += (size_t)640*256*2;       // 320 KB
  float* bias_all = (float*)ws;                                 // 2.5 KB

  k1_weights <<<640,          256, 0, stream>>>(wq, bq, wk, bk, wv, bv, w128, Wf, bias_all);
  k2_features<<<dim3(256, 2), 256, 0, stream>>>(x4, x3, Wf, bias_all, Qf8, Kf8, V);
  k3_smax    <<<512,          256, 0, stream>>>(Qf8, Kf8, Pm);
  k5_out     <<<4096,         256, 0, stream>>>(V, Pm, b128, out);
}